// Round 14
// baseline (111.672 us; speedup 1.0000x reference)
//
#include <hip/hip_runtime.h>
#include <hip/hip_bf16.h>

typedef __attribute__((ext_vector_type(8))) short short8;
typedef __attribute__((ext_vector_type(4))) float f32x4;

#define N_U 8192
#define N_I 8192
#define KD  256

// ws float-slot layout: [0,4096) gemm err; [4096,4608) pack_a; [4608,6656)
// pack_v. All written unconditionally every launch (plain stores, no atomics).
#define ERR_SLOTS 4096
#define REGA_BASE 4096
#define REGV_BASE 4608
#define SLOTS_END 6656

// global_load_lds, 16B per lane.
#define GLD16(g, l) __builtin_amdgcn_global_load_lds( \
    (const __attribute__((address_space(1))) unsigned int*)(unsigned long long)(uintptr_t)(g), \
    (__attribute__((address_space(3))) unsigned int*)(unsigned int)(uintptr_t)(l), 16, 0, 0)

static __device__ __forceinline__ unsigned short f2bf(float x) {
  unsigned u = __builtin_bit_cast(unsigned, x);
  u += 0x7fffu + ((u >> 16) & 1u);   // round-to-nearest-even
  return (unsigned short)(u >> 16);
}

static __device__ __forceinline__ void block_reduce_store(float v, float* slot) {
  #pragma unroll
  for (int off = 32; off > 0; off >>= 1) v += __shfl_down(v, off, 64);
  __shared__ float red[4];
  int lane = threadIdx.x & 63, wv = threadIdx.x >> 6;
  if (lane == 0) red[wv] = v;
  __syncthreads();
  if (threadIdx.x == 0) *slot = red[0] + red[1] + red[2] + red[3];
}

// A = P.T (elementwise*) U  -> bf16 [N_U][KD]; partial sum(U^2)+sum(P^2) to slot.
__global__ __launch_bounds__(256) void pack_a_kernel(
    const float* __restrict__ U, const float* __restrict__ P,
    unsigned short* __restrict__ Abf, float* __restrict__ ws)
{
  __shared__ float Pt[64][65];   // +1 pad
  const int u0 = blockIdx.x * 64;
  const int k0 = blockIdx.y * 64;
  const int t = threadIdx.x;
  float ss = 0.f;
  {
    const int ul4 = (t & 15) * 4, klb = t >> 4;
    #pragma unroll
    for (int pass = 0; pass < 4; ++pass) {
      int kl = klb + pass * 16;
      float4 pv = *(const float4*)&P[(size_t)(k0 + kl) * N_U + u0 + ul4];
      Pt[kl][ul4 + 0] = pv.x; Pt[kl][ul4 + 1] = pv.y;
      Pt[kl][ul4 + 2] = pv.z; Pt[kl][ul4 + 3] = pv.w;
      ss += pv.x * pv.x + pv.y * pv.y + pv.z * pv.z + pv.w * pv.w;
    }
  }
  __syncthreads();
  {
    const int k4 = (t & 15) * 4, ulb = t >> 4;
    #pragma unroll
    for (int pass = 0; pass < 4; ++pass) {
      int ul = ulb + pass * 16;
      float4 uv = *(const float4*)&U[(size_t)(u0 + ul) * KD + k0 + k4];
      ss += uv.x * uv.x + uv.y * uv.y + uv.z * uv.z + uv.w * uv.w;
      ushort4 w;
      w.x = f2bf(uv.x * Pt[k4 + 0][ul]);
      w.y = f2bf(uv.y * Pt[k4 + 1][ul]);
      w.z = f2bf(uv.z * Pt[k4 + 2][ul]);
      w.w = f2bf(uv.w * Pt[k4 + 3][ul]);
      *(ushort4*)&Abf[(size_t)(u0 + ul) * KD + k0 + k4] = w;
    }
  }
  block_reduce_store(ss, ws + REGA_BASE + blockIdx.y * 128 + blockIdx.x);
}

// V -> bf16; partial sum(V^2) to slot.
__global__ __launch_bounds__(256) void pack_v_kernel(
    const float* __restrict__ V, unsigned short* __restrict__ Vbf,
    float* __restrict__ ws)
{
  size_t i = ((size_t)blockIdx.x * 256 + threadIdx.x) * 4;
  float4 v = *(const float4*)&V[i];
  float ss = v.x * v.x + v.y * v.y + v.z * v.z + v.w * v.w;
  ushort4 w;
  w.x = f2bf(v.x); w.y = f2bf(v.y); w.z = f2bf(v.z); w.w = f2bf(v.w);
  *(ushort4*)&Vbf[i] = w;
  block_reduce_store(ss, ws + REGV_BASE + blockIdx.x);
}

// 128x128 tile, BK=32, 4 waves (2x2), swapped-operand mfma.
// R14 = R6 structure + three composed fixes:
//  (1) R-overlap: 2 plain global->VGPR float4 R loads per K-iter, spread
//      across all 8 iters. They retire concurrently with the panel staging
//      the barrier was already draining (cost = max, not sum), so by the
//      epilogue the whole 64KB R tile is in registers. No LDS dest, no
//      vmcnt bookkeeping — the R5/R7/R8 failure modes are absent.
//  (2) R12's verified LDS k-slot XOR swizzle (8-way -> ~2-way on the
//      ds_read_b128 fragment reads; source pre-swizzled, GLD dest linear).
//  (3) Double-buffered LDS: ONE __syncthreads per iter.
__global__ __launch_bounds__(256) void gemm_loss_kernel(
    const float* __restrict__ R, const unsigned short* __restrict__ Abf,
    const unsigned short* __restrict__ Vbf, float* __restrict__ ws)
{
  __shared__ unsigned short As[2][128 * 32];   // 16 KB
  __shared__ unsigned short Bs[2][128 * 32];   // 16 KB
  const int tid = threadIdx.x;
  const int wv = tid >> 6, lane = tid & 63;
  const int brow = blockIdx.x, bcol = blockIdx.y;
  const int wr = wv >> 1, wc = wv & 1;

  f32x4 acc[4][4] = {};
  float4 rreg[16];

  const unsigned short* Ag = Abf + (size_t)brow * 128 * KD;
  const unsigned short* Bg = Vbf + (size_t)bcol * 128 * KD;
  const int f0 = wv * 128 + lane;   // LDS chunk positions; f0,f1 cover [0,512)
  const int f1 = f0 + 64;
  // source k-slot pre-swizzle for position f: ks = (f&3) ^ ((f>>3)&3)
  const int sw0 = (((f0 & 3) ^ ((f0 >> 3) & 3)) * 8);
  const int sw1 = (((f1 & 3) ^ ((f1 >> 3) & 3)) * 8);
  const int r0 = lane & 15;
  // read-side: k-slot q of row r lives at chunk (q ^ ((r0>>1)&3)) of the row
  const int kq = (((lane >> 4) ^ ((r0 >> 1) & 3)) * 8);

  // Epilogue mapping (R6-verified swapped-operand):
  //   pred_row = brow*128 + wr*64 + m*16 + (lane&15)
  //   pred_col = bcol*128 + wc*64 + n*16 + (lane>>4)*4 + j
  const int row0 = brow * 128 + wr * 64 + r0;
  const size_t col0 = (size_t)bcol * 128 + wc * 64 + (lane >> 4) * 4;
  const float* Rtile = R + (size_t)row0 * N_I + col0;

#define STAGE(buf, kt) do { \
    GLD16(Ag + ((f0 >> 2) * KD + (kt)) + sw0, &As[buf][f0 * 8]); \
    GLD16(Bg + ((f0 >> 2) * KD + (kt)) + sw0, &Bs[buf][f0 * 8]); \
    GLD16(Ag + ((f1 >> 2) * KD + (kt)) + sw1, &As[buf][f1 * 8]); \
    GLD16(Bg + ((f1 >> 2) * KD + (kt)) + sw1, &Bs[buf][f1 * 8]); \
  } while (0)

  // prologue: stage K-tile 0 into buf 0 (syncthreads drains it).
  STAGE(0, 0);
  __syncthreads();

  #pragma unroll
  for (int t = 0; t < 8; ++t) {
    const int cur = t & 1;
    if (t < 7) STAGE(cur ^ 1, (t + 1) * 32);
    // 2 R float4 loads, spread: indices 2t, 2t+1 -> (m = i>>2, n = i&3).
    {
      const int i0 = 2 * t, i1 = 2 * t + 1;
      rreg[i0] = *(const float4*)(Rtile + (size_t)((i0 >> 2) * 16) * N_I + (i0 & 3) * 16);
      rreg[i1] = *(const float4*)(Rtile + (size_t)((i1 >> 2) * 16) * N_I + (i1 & 3) * 16);
    }
    short8 a[4], b[4];
    #pragma unroll
    for (int m = 0; m < 4; ++m)
      a[m] = *(const short8*)&As[cur][(wr * 64 + m * 16 + r0) * 32 + kq];
    #pragma unroll
    for (int n = 0; n < 4; ++n)
      b[n] = *(const short8*)&Bs[cur][(wc * 64 + n * 16 + r0) * 32 + kq];
    #pragma unroll
    for (int m = 0; m < 4; ++m)
      #pragma unroll
      for (int n = 0; n < 4; ++n)
        acc[m][n] = __builtin_amdgcn_mfma_f32_16x16x32_bf16(b[n], a[m], acc[m][n], 0, 0, 0);
    __syncthreads();   // drains staging (and this iter's R pair, concurrently)
  }
#undef STAGE

  // Register-only masked-SSE epilogue.
  float lsum = 0.f;
  #pragma unroll
  for (int i = 0; i < 16; ++i) {
    const int m = i >> 2, n = i & 3;
    float4 rv = rreg[i];
    if (rv.x != 0.f) { float d = rv.x - acc[m][n][0]; lsum += d * d; }
    if (rv.y != 0.f) { float d = rv.y - acc[m][n][1]; lsum += d * d; }
    if (rv.z != 0.f) { float d = rv.z - acc[m][n][2]; lsum += d * d; }
    if (rv.w != 0.f) { float d = rv.w - acc[m][n][3]; lsum += d * d; }
  }

  // block reduce, reusing As (fully consumed) as scratch.
  #pragma unroll
  for (int off = 32; off > 0; off >>= 1) lsum += __shfl_down(lsum, off, 64);
  float* red = (float*)As;
  __syncthreads();
  if (lane == 0) red[wv] = lsum;
  __syncthreads();
  if (tid == 0) ws[blockIdx.y * 64 + blockIdx.x] = red[0] + red[1] + red[2] + red[3];
}

// Reduce all slots: out = err/2 + 0.1/2 * regsum.
__global__ __launch_bounds__(256) void finalize_kernel(
    const float* __restrict__ ws, float* __restrict__ out)
{
  __shared__ float sh[256];
  const int tid = threadIdx.x;
  float e = 0.f, r = 0.f;
  for (int i = tid; i < ERR_SLOTS; i += 256) e += ws[i];
  for (int i = REGA_BASE + tid; i < SLOTS_END; i += 256) r += ws[i];
  sh[tid] = 0.5f * e + 0.05f * r;
  __syncthreads();
  #pragma unroll
  for (int s = 128; s > 0; s >>= 1) {
    if (tid < s) sh[tid] += sh[tid + s];
    __syncthreads();
  }
  if (tid == 0) out[0] = sh[0];
}

extern "C" void kernel_launch(void* const* d_in, const int* in_sizes, int n_in,
                              void* d_out, int out_size, void* d_ws, size_t ws_size,
                              hipStream_t stream) {
  const float* R = (const float*)d_in[0];
  const float* U = (const float*)d_in[1];
  const float* V = (const float*)d_in[2];
  // d_in[3]=alpha, d_in[4]=Y, d_in[6]=Q: dead w.r.t. the returned value.
  const float* P = (const float*)d_in[5];

  float* ws = (float*)d_ws;                                           // slots
  unsigned short* Abf = (unsigned short*)((char*)d_ws + (1 << 20));   // 4 MiB
  unsigned short* Vbf = Abf + (size_t)N_U * KD;                       // 4 MiB
  float* out = (float*)d_out;

  pack_a_kernel<<<dim3(N_U / 64, KD / 64), 256, 0, stream>>>(U, P, Abf, ws);
  pack_v_kernel<<<dim3((N_I * KD) / (256 * 4)), 256, 0, stream>>>(V, Vbf, ws);
  gemm_loss_kernel<<<dim3(64, 64), 256, 0, stream>>>(R, Abf, Vbf, ws);
  finalize_kernel<<<1, 256, 0, stream>>>(ws, out);
}